// Round 2
// baseline (259.639 us; speedup 1.0000x reference)
//
#include <hip/hip_runtime.h>

// Sizes fixed by the problem.
#define BS    64
#define KDIM  256   // in_dim
#define ICAP  256   // I = 16*16
#define JCAP  64    // J out-caps
#define D2    32
#define OUTD  2048  // J*D2

typedef short bf16x8 __attribute__((ext_vector_type(8)));
typedef float f32x4  __attribute__((ext_vector_type(4)));

static __device__ __forceinline__ float bf2f(unsigned u16) {
  union { unsigned u; float f; } v; v.u = u16 << 16; return v.f;
}
static __device__ __forceinline__ unsigned short f2bf(float x) {
  union { float f; unsigned u; } v; v.f = x;
  unsigned r = v.u + 0x7fffu + ((v.u >> 16) & 1u);
  return (unsigned short)(r >> 16);
}
static __device__ __forceinline__ void unpack8(uint4 u, float* f) {
  f[0] = bf2f(u.x & 0xffffu); f[1] = bf2f(u.x >> 16);
  f[2] = bf2f(u.y & 0xffffu); f[3] = bf2f(u.y >> 16);
  f[4] = bf2f(u.z & 0xffffu); f[5] = bf2f(u.z >> 16);
  f[6] = bf2f(u.w & 0xffffu); f[7] = bf2f(u.w >> 16);
}

// ---------------------------------------------------------------------------
// prep_w: W f32 -> Wbf bf16 [OUTD][KDIM]. 256 blocks x 256 thr x 8 elems.
// ---------------------------------------------------------------------------
__global__ __launch_bounds__(256) void prep_w(
    const float* __restrict__ W, unsigned short* __restrict__ Wbf)
{
  const int g = blockIdx.x * 256 + threadIdx.x;
  const float* s = W + (size_t)g * 8;
  f32x4 a = *(const f32x4*)s;
  f32x4 b = *(const f32x4*)(s + 4);
  uint4 o;
  o.x = (unsigned)f2bf(a.x) | ((unsigned)f2bf(a.y) << 16);
  o.y = (unsigned)f2bf(a.z) | ((unsigned)f2bf(a.w) << 16);
  o.z = (unsigned)f2bf(b.x) | ((unsigned)f2bf(b.y) << 16);
  o.w = (unsigned)f2bf(b.z) | ((unsigned)f2bf(b.w) << 16);
  *(uint4*)(Wbf + (size_t)g * 8) = o;
}

// ---------------------------------------------------------------------------
// mega: one block per b. 1024 threads (16 waves). All routing passes fused.
//   P0 : x[b] f32 -> xT[b] (i,k) bf16 + xKI[b] (k,i) bf16 (global, self-use)
//   C0 : c = softmax_j(Binit[b]) -> LDS c[j][i] bf16 + csum[j]
//   per pass p=1..3:
//     Y  : Yt[j][k] = sum_i xKI[k][i]*c[j][i]            (MFMA)
//     s  : s[jd] = sum_k Wbf[jd][k]*Yt[j][k] + csum[j]*Wb[jd]; squash -> v
//          (pass 3: write v to out, done)
//     U  : U[j][k] = sum_d v[j][d]*Wbf[j*32+d][k]  (bf16 hi+lo in LDS)
//     db : db[i][j] = sum_k xT[i][k]*U[j][k] (MFMA hi+lo); b += db + ub;
//          softmax over j in-register -> c, csum.  b-logits stay in VGPRs.
// ---------------------------------------------------------------------------
__global__ __launch_bounds__(1024) void mega(
    const float* __restrict__ x,           // [BS][KDIM][ICAP] f32
    const float* __restrict__ Binit,       // [BS][JCAP][ICAP] f32
    const unsigned short* __restrict__ Wbf,// [OUTD][KDIM] bf16
    const float* __restrict__ Wb,          // [OUTD] f32
    unsigned short* __restrict__ xT,       // [BS][ICAP][KDIM] bf16
    unsigned short* __restrict__ xKI,      // [BS][KDIM][ICAP] bf16
    float* __restrict__ outp)              // [BS][OUTD] f32
{
  __shared__ struct {
    unsigned short c[64][264];             // 33,792 B (persistent)
    union {
      float xs[64][260];                   // x/Binit staging (66,560)
      float yt[64][260];                   // Y^T [j][k] f32  (66,560)
      unsigned short u[2][64][264];        // U hi/lo bf16    (67,584)
    } big;
    float v[64][34];                       // 8,704
    float ub[64];
    float csum[64];
    float red[16][64];                     // per-wave csum partials (4,096)
  } sm;                                    // total ~114.7 KB -> 1 block/CU

  const int t   = threadIdx.x;
  const int b   = blockIdx.x;
  const int l   = t & 63;
  const int w   = t >> 6;
  const int l15 = l & 15;
  const int lhi = l >> 4;

  // ---------------- P0: cast/transpose x ----------------
  for (int kt = 0; kt < 4; ++kt) {
    const int k0 = kt * 64;
    {
      const int r  = t >> 4;
      const int c4 = (t & 15) * 16;
      const float* src = x + ((size_t)(b * KDIM + k0 + r) * ICAP) + c4;
#pragma unroll
      for (int q = 0; q < 4; ++q)
        *(f32x4*)&sm.big.xs[r][c4 + q * 4] = *(const f32x4*)(src + q * 4);
    }
    __syncthreads();
    {   // xT[b][i][k0+kq..+16]
      const int i  = t >> 2;
      const int kq = (t & 3) * 16;
      unsigned pk[8];
#pragma unroll
      for (int h = 0; h < 8; ++h)
        pk[h] = (unsigned)f2bf(sm.big.xs[kq + 2 * h][i]) |
                ((unsigned)f2bf(sm.big.xs[kq + 2 * h + 1][i]) << 16);
      unsigned short* dst = xT + ((size_t)(b * ICAP + i) * KDIM) + k0 + kq;
      uint4 s0; s0.x = pk[0]; s0.y = pk[1]; s0.z = pk[2]; s0.w = pk[3];
      uint4 s1; s1.x = pk[4]; s1.y = pk[5]; s1.z = pk[6]; s1.w = pk[7];
      *(uint4*)dst       = s0;
      *(uint4*)(dst + 8) = s1;
    }
    {   // xKI[b][k0+k][is..+16]
      const int k  = t >> 4;
      const int is = (t & 15) * 16;
      unsigned pk[8];
#pragma unroll
      for (int h = 0; h < 8; ++h)
        pk[h] = (unsigned)f2bf(sm.big.xs[k][is + 2 * h]) |
                ((unsigned)f2bf(sm.big.xs[k][is + 2 * h + 1]) << 16);
      unsigned short* dst = xKI + ((size_t)(b * KDIM + k0 + k) * ICAP) + is;
      uint4 s0; s0.x = pk[0]; s0.y = pk[1]; s0.z = pk[2]; s0.w = pk[3];
      uint4 s1; s1.x = pk[4]; s1.y = pk[5]; s1.z = pk[6]; s1.w = pk[7];
      *(uint4*)dst       = s0;
      *(uint4*)(dst + 8) = s1;
    }
    __syncthreads();
  }

  // ---------------- C0: softmax of Binit -> c, csum ----------------
  {
    const int r  = t >> 4;
    const int c4 = (t & 15) * 16;
    const float* src = Binit + ((size_t)(b * JCAP + r) * ICAP) + c4;
#pragma unroll
    for (int q = 0; q < 4; ++q)
      *(f32x4*)&sm.big.xs[r][c4 + q * 4] = *(const f32x4*)(src + q * 4);
  }
  __syncthreads();
  {
    const int i  = t >> 2;
    const int j0 = (t & 3) * 16;
    float m = -3.0e38f;
#pragma unroll
    for (int jj = 0; jj < 16; ++jj) m = fmaxf(m, sm.big.xs[j0 + jj][i]);
    m = fmaxf(m, __shfl_xor(m, 1, 64));
    m = fmaxf(m, __shfl_xor(m, 2, 64));
    float se = 0.f;
#pragma unroll
    for (int jj = 0; jj < 16; ++jj) se += __expf(sm.big.xs[j0 + jj][i] - m);
    se += __shfl_xor(se, 1, 64);
    se += __shfl_xor(se, 2, 64);
    const float inv = 1.0f / se;
#pragma unroll
    for (int jj = 0; jj < 16; ++jj)
      sm.c[j0 + jj][i] = f2bf(__expf(sm.big.xs[j0 + jj][i] - m) * inv);
  }
  __syncthreads();
  {   // csum[j] = sum_i c[j][i]
    const int j  = t >> 4;
    const int is = (t & 15) * 16;
    float s = 0.f;
#pragma unroll
    for (int e = 0; e < 16; ++e) s += bf2f(sm.c[j][is + e]);
    s += __shfl_xor(s, 1, 64);
    s += __shfl_xor(s, 2, 64);
    s += __shfl_xor(s, 4, 64);
    s += __shfl_xor(s, 8, 64);
    if ((t & 15) == 0) sm.csum[j] = s;
  }
  __syncthreads();

  // ---------------- routing passes ----------------
  float blogreg[16];   // b-logits for lane's (j=n*16+l15, i=w*16+lhi*4+r)

  for (int pass = 1; pass <= 3; ++pass) {
    // ---- Y-phase: Yt[j][k] = sum_i xKI[k][i]*c[j][i] ----
    {
      f32x4 acc[4];
#pragma unroll
      for (int n = 0; n < 4; ++n) acc[n] = (f32x4){0.f, 0.f, 0.f, 0.f};
      const unsigned short* Ap =
          xKI + ((size_t)(b * KDIM + w * 16 + l15)) * ICAP + lhi * 8;
#pragma unroll
      for (int ks = 0; ks < 8; ++ks) {
        bf16x8 a = *(const bf16x8*)(Ap + ks * 32);
#pragma unroll
        for (int n = 0; n < 4; ++n) {
          bf16x8 bb = *(const bf16x8*)&sm.c[n * 16 + l15][lhi * 8 + ks * 32];
          acc[n] = __builtin_amdgcn_mfma_f32_16x16x32_bf16(a, bb, acc[n], 0, 0, 0);
        }
      }
      // D: m=k=(w*16+lhi*4+r), n=j -> write transposed Yt[j][k], b128
#pragma unroll
      for (int n = 0; n < 4; ++n)
        *(f32x4*)&sm.big.yt[n * 16 + l15][w * 16 + lhi * 4] = acc[n];
    }
    __syncthreads();

    // ---- s-phase + squash (+ output on pass 3) ----
    {
      const int j   = t >> 4;
      const int d0  = (t & 15) * 2;
      const int jd0 = j * 32 + d0;
      float s0 = 0.f, s1 = 0.f;
      const unsigned short* w0 = Wbf + (size_t)jd0 * KDIM;
      const float* yr = &sm.big.yt[j][0];
      for (int k8 = 0; k8 < 32; ++k8) {
        uint4 u0 = *(const uint4*)(w0 + k8 * 8);
        uint4 u1 = *(const uint4*)(w0 + KDIM + k8 * 8);
        float f0[8], f1[8];
        unpack8(u0, f0); unpack8(u1, f1);
        f32x4 y0 = *(const f32x4*)(yr + k8 * 8);
        f32x4 y1 = *(const f32x4*)(yr + k8 * 8 + 4);
        s0 += f0[0]*y0.x + f0[1]*y0.y + f0[2]*y0.z + f0[3]*y0.w
            + f0[4]*y1.x + f0[5]*y1.y + f0[6]*y1.z + f0[7]*y1.w;
        s1 += f1[0]*y0.x + f1[1]*y0.y + f1[2]*y0.z + f1[3]*y0.w
            + f1[4]*y1.x + f1[5]*y1.y + f1[6]*y1.z + f1[7]*y1.w;
      }
      const float wbx = Wb[jd0], wby = Wb[jd0 + 1];
      const float cs  = sm.csum[j];
      s0 += cs * wbx; s1 += cs * wby;
      float sq = s0 * s0 + s1 * s1;
      sq += __shfl_xor(sq, 1, 64);
      sq += __shfl_xor(sq, 2, 64);
      sq += __shfl_xor(sq, 4, 64);
      sq += __shfl_xor(sq, 8, 64);
      const float scale = (sq / (1.0f + sq)) / sqrtf(sq + 1e-8f);
      const float v0 = scale * s0, v1 = scale * s1;
      if (pass == 3) {
        float2 o; o.x = v0; o.y = v1;
        *(float2*)(outp + (size_t)b * OUTD + jd0) = o;
      } else {
        sm.v[j][d0]     = v0;
        sm.v[j][d0 + 1] = v1;
        float up = v0 * wbx + v1 * wby;
        up += __shfl_xor(up, 1, 64);
        up += __shfl_xor(up, 2, 64);
        up += __shfl_xor(up, 4, 64);
        up += __shfl_xor(up, 8, 64);
        if ((t & 15) == 0) sm.ub[j] = up;
      }
    }
    if (pass == 3) return;
    __syncthreads();

    // ---- U-phase: U[j][k] = sum_d v[j][d]*Wbf[j*32+d][k], hi+lo bf16 ----
    {
      const int j  = t >> 4;
      const int ks = (t & 15) * 16;
      float acc[16];
#pragma unroll
      for (int e = 0; e < 16; ++e) acc[e] = 0.f;
      const unsigned short* wr = Wbf + ((size_t)j * 32) * KDIM + ks;
      for (int d = 0; d < 32; ++d) {
        const float vd = sm.v[j][d];
        uint4 u0 = *(const uint4*)(wr + (size_t)d * KDIM);
        uint4 u1 = *(const uint4*)(wr + (size_t)d * KDIM + 8);
        float f[16]; unpack8(u0, f); unpack8(u1, f + 8);
#pragma unroll
        for (int e = 0; e < 16; ++e) acc[e] += vd * f[e];
      }
      unsigned ph[8], pl[8];
#pragma unroll
      for (int h = 0; h < 8; ++h) {
        unsigned short h0 = f2bf(acc[2 * h]), h1 = f2bf(acc[2 * h + 1]);
        float r0 = acc[2 * h] - bf2f(h0), r1 = acc[2 * h + 1] - bf2f(h1);
        ph[h] = (unsigned)h0 | ((unsigned)h1 << 16);
        pl[h] = (unsigned)f2bf(r0) | ((unsigned)f2bf(r1) << 16);
      }
      uint4 q0; q0.x = ph[0]; q0.y = ph[1]; q0.z = ph[2]; q0.w = ph[3];
      uint4 q1; q1.x = ph[4]; q1.y = ph[5]; q1.z = ph[6]; q1.w = ph[7];
      *(uint4*)&sm.big.u[0][j][ks]     = q0;
      *(uint4*)&sm.big.u[0][j][ks + 8] = q1;
      uint4 q2; q2.x = pl[0]; q2.y = pl[1]; q2.z = pl[2]; q2.w = pl[3];
      uint4 q3; q3.x = pl[4]; q3.y = pl[5]; q3.z = pl[6]; q3.w = pl[7];
      *(uint4*)&sm.big.u[1][j][ks]     = q2;
      *(uint4*)&sm.big.u[1][j][ks + 8] = q3;
    }
    __syncthreads();

    // ---- db-phase: MFMA + in-register softmax -> c, csum ----
    {
      f32x4 acc[4];
#pragma unroll
      for (int n = 0; n < 4; ++n) acc[n] = (f32x4){0.f, 0.f, 0.f, 0.f};
      const unsigned short* Ap =
          xT + ((size_t)(b * ICAP + w * 16 + l15)) * KDIM + lhi * 8;
#pragma unroll
      for (int ks = 0; ks < 8; ++ks) {
        bf16x8 a = *(const bf16x8*)(Ap + ks * 32);
#pragma unroll
        for (int n = 0; n < 4; ++n) {
          bf16x8 bh = *(const bf16x8*)&sm.big.u[0][n * 16 + l15][lhi * 8 + ks * 32];
          acc[n] = __builtin_amdgcn_mfma_f32_16x16x32_bf16(a, bh, acc[n], 0, 0, 0);
          bf16x8 bl = *(const bf16x8*)&sm.big.u[1][n * 16 + l15][lhi * 8 + ks * 32];
          acc[n] = __builtin_amdgcn_mfma_f32_16x16x32_bf16(a, bl, acc[n], 0, 0, 0);
        }
      }
      if (pass == 1) {
#pragma unroll
        for (int n = 0; n < 4; ++n)
#pragma unroll
          for (int r = 0; r < 4; ++r)
            blogreg[n * 4 + r] =
                Binit[((size_t)(b * JCAP + n * 16 + l15)) * ICAP + w * 16 + lhi * 4 + r];
      }
#pragma unroll
      for (int n = 0; n < 4; ++n) {
        const float ubn = sm.ub[n * 16 + l15];
#pragma unroll
        for (int r = 0; r < 4; ++r)
          blogreg[n * 4 + r] += acc[n][r] + ubn;
      }
      float cpart[4] = {0.f, 0.f, 0.f, 0.f};
#pragma unroll
      for (int r = 0; r < 4; ++r) {
        float b0 = blogreg[r], b1 = blogreg[4 + r];
        float b2 = blogreg[8 + r], b3 = blogreg[12 + r];
        float mx = fmaxf(fmaxf(b0, b1), fmaxf(b2, b3));
        mx = fmaxf(mx, __shfl_xor(mx, 1, 64));
        mx = fmaxf(mx, __shfl_xor(mx, 2, 64));
        mx = fmaxf(mx, __shfl_xor(mx, 4, 64));
        mx = fmaxf(mx, __shfl_xor(mx, 8, 64));
        float e0 = __expf(b0 - mx), e1 = __expf(b1 - mx);
        float e2 = __expf(b2 - mx), e3 = __expf(b3 - mx);
        float se = e0 + e1 + e2 + e3;
        se += __shfl_xor(se, 1, 64);
        se += __shfl_xor(se, 2, 64);
        se += __shfl_xor(se, 4, 64);
        se += __shfl_xor(se, 8, 64);
        const float inv = 1.0f / se;
        const int i = w * 16 + lhi * 4 + r;
        const float c0v = e0 * inv, c1v = e1 * inv, c2v = e2 * inv, c3v = e3 * inv;
        sm.c[l15][i]      = f2bf(c0v);
        sm.c[16 + l15][i] = f2bf(c1v);
        sm.c[32 + l15][i] = f2bf(c2v);
        sm.c[48 + l15][i] = f2bf(c3v);
        cpart[0] += c0v; cpart[1] += c1v; cpart[2] += c2v; cpart[3] += c3v;
      }
#pragma unroll
      for (int n = 0; n < 4; ++n) {
        cpart[n] += __shfl_xor(cpart[n], 16, 64);
        cpart[n] += __shfl_xor(cpart[n], 32, 64);
      }
      if (lhi == 0) {
#pragma unroll
        for (int n = 0; n < 4; ++n) sm.red[w][n * 16 + l15] = cpart[n];
      }
    }
    __syncthreads();
    if (t < 64) {
      float s = 0.f;
#pragma unroll
      for (int ww = 0; ww < 16; ++ww) s += sm.red[ww][t];
      sm.csum[t] = s;
    }
    __syncthreads();
  }
}

// ---------------------------------------------------------------------------
extern "C" void kernel_launch(void* const* d_in, const int* in_sizes, int n_in,
                              void* d_out, int out_size, void* d_ws, size_t ws_size,
                              hipStream_t stream) {
  const float* x  = (const float*)d_in[0];
  const float* bi = (const float*)d_in[1];
  const float* W  = (const float*)d_in[2];
  const float* Wb = (const float*)d_in[3];
  float* out = (float*)d_out;

  char* ws = (char*)d_ws;
  const size_t MiB = 1024 * 1024;
  unsigned short* xT  = (unsigned short*)(ws + 0 * MiB);    // 8 MiB
  unsigned short* xKI = (unsigned short*)(ws + 8 * MiB);    // 8 MiB
  unsigned short* Wbf = (unsigned short*)(ws + 16 * MiB);   // 1 MiB

  prep_w<<<dim3(256), 256, 0, stream>>>(W, Wbf);
  mega<<<dim3(64), 1024, 0, stream>>>(x, bi, Wbf, Wb, xT, xKI, out);
}